// Round 14
// baseline (211.851 us; speedup 1.0000x reference)
//
#include <hip/hip_runtime.h>
#include <hip/hip_bf16.h>
#include <math.h>

#define N_NODES 50000
#define N_EDGES 600000
#define N_GRAPHS 1024
#define H 128
#define VOCAB 32
#define BN_EPS 1e-5f
#define SCAN_BLOCKS ((N_NODES + 255) / 256)   // 196
#define H1_NODES 64
#define EB ((N_EDGES + 255) / 256)            // 2344
#define GM_NODES 16
#define SROW 136   // LDS row stride in bf16 elems (272 B = 17*16, 2-way bank aliasing only)
#define ZERO_BYTES (N_NODES * sizeof(int) + (size_t)N_NODES * VOCAB * 8)  // cntO + wc, 13.0 MB
#define ZERO_N16 ((int)(ZERO_BYTES / 16))

typedef short bf8_t __attribute__((ext_vector_type(8)));
typedef float f4_t __attribute__((ext_vector_type(4)));

// ---------------- pass 0: zero cntO + wc (rocclr fill kernel is ~20x too slow) ----------------
__global__ void k_zero(uint4* __restrict__ p, int n16) {
    int i = blockIdx.x * blockDim.x + threadIdx.x;
    if (i < n16) p[i] = uint4{0u, 0u, 0u, 0u};
}

// ---------------- pass 1: out-degree count + weight prep (fused) ----------------
__global__ void k_count_prep(const int* __restrict__ src, int* __restrict__ cntO,
                             const float* __restrict__ emb, const float* __restrict__ W1,
                             float* __restrict__ emb1,
                             const float* __restrict__ W2, __hip_bfloat16* __restrict__ w2t) {
    int b = blockIdx.x;
    int t = threadIdx.x;
    if (b < EB) {
        int i = b * 256 + t;
        if (i < N_EDGES) atomicAdd(&cntO[src[i]], 1);
    } else if (b < EB + 32) {
        if (t < 128) {
            int v = b - EB;
            float acc = 0.f;
            for (int k = 0; k < H; ++k) acc += emb[v * H + k] * W1[k * H + t];
            emb1[v * H + t] = acc;
        }
    } else {
        if (t < 128) {
            int k = b - EB - 32;
            w2t[(size_t)t * H + k] = __float2bfloat16(W2[(size_t)k * H + t]);
        }
    }
}

// ---------------- pass 2: fused weighted histogram + in-degree (64-bit atomics) ----------------
__global__ void k_hist64(const int* __restrict__ src, const int* __restrict__ dst,
                         const int* __restrict__ feat, const int* __restrict__ cntO,
                         unsigned long long* __restrict__ wc,
                         unsigned char* __restrict__ rank8, int E) {
    int i = blockIdx.x * blockDim.x + threadIdx.x;
    if (i >= E) return;
    int s = src[i], d = dst[i], v = feat[s];
    float o = rsqrtf(fmaxf((float)cntO[s], 1.f));
    unsigned long long q = (unsigned long long)__float2uint_rn(o * 16777216.0f);
    unsigned long long old = atomicAdd(&wc[(size_t)d * VOCAB + v], (1ULL << 40) | q);
    rank8[i] = (unsigned char)(old >> 40);
}

// ---------------- pass 3: per-node bin scan + cntI + per-256-node block sums ----------------
__global__ void k_nodebins(const unsigned long long* __restrict__ wc,
                           int* __restrict__ cntI, unsigned char* __restrict__ binbase,
                           int* __restrict__ bsum, int n) {
    __shared__ int scnt[256];
    int t = threadIdx.x;
    int wave = t >> 6, lane = t & 63;
    int sub = lane >> 5;
    int l32 = lane & 31;
    int nodeBase = blockIdx.x * 256;
#pragma unroll 4
    for (int it = 0; it < 32; ++it) {
        int local = wave * 64 + it * 2 + sub;
        int node = nodeBase + local;
        int c = 0;
        if (node < n && l32 < VOCAB)
            c = (int)(wc[(size_t)node * VOCAB + l32] >> 40);
        int inc = c;
#pragma unroll
        for (int off = 1; off < VOCAB; off <<= 1) {
            int u = __shfl_up(inc, off, 32);
            if (l32 >= off) inc += u;
        }
        if (node < n && l32 < VOCAB)
            binbase[(size_t)node * VOCAB + l32] = (unsigned char)(inc - c);
        if (l32 == VOCAB - 1) scnt[local] = (node < n) ? inc : 0;
    }
    __syncthreads();
    int node = nodeBase + t;
    if (node < n) cntI[node] = scnt[t];
    __shared__ int red[256];
    red[t] = scnt[t];
    __syncthreads();
    for (int off = 128; off > 0; off >>= 1) {
        if (t < off) red[t] += red[t + off];
        __syncthreads();
    }
    if (t == 0) bsum[blockIdx.x] = red[0];
}

// ---------------- pass 4: scatter-scan with inline (redundant) bsum scan ----------------
__global__ void k_scatterscan(const int* __restrict__ cntI, const int* __restrict__ bsum,
                              int* __restrict__ row_ptr, float* __restrict__ ii,
                              int n, int nb) {
    __shared__ int sb[256];
    __shared__ int sh[256];
    int t = threadIdx.x;
    int bv = (t < nb) ? bsum[t] : 0;
    sb[t] = bv;
    __syncthreads();
    for (int off = 1; off < 256; off <<= 1) {
        int u = (t >= off) ? sb[t - off] : 0;
        __syncthreads();
        sb[t] += u;
        __syncthreads();
    }
    int blockoff = (blockIdx.x == 0) ? 0 : sb[blockIdx.x - 1];
    int i = blockIdx.x * 256 + t;
    int v = (i < n) ? cntI[i] : 0;
    sh[t] = v;
    __syncthreads();
    for (int off = 1; off < 256; off <<= 1) {
        int u = (t >= off) ? sh[t - off] : 0;
        __syncthreads();
        sh[t] += u;
        __syncthreads();
    }
    if (i < n) {
        row_ptr[i] = blockoff + sh[t] - v;
        ii[i] = rsqrtf(fmaxf((float)v, 1.f));
    }
    if (blockIdx.x == 0 && t == 0) row_ptr[n] = sb[nb - 1];
}

// ---------------- pass 5 (fused): atomic-free CSR fill + layer-1 h1 compute ----------------
#define H1_BLOCKS ((N_NODES + H1_NODES - 1) / H1_NODES)   // 782
__global__ void k_fill_h1(const int* __restrict__ src, const int* __restrict__ dst,
                          const int* __restrict__ feat, const int* __restrict__ row_ptr,
                          const unsigned char* __restrict__ binbase,
                          const unsigned char* __restrict__ rank8,
                          int* __restrict__ col,
                          const unsigned long long* __restrict__ wc,
                          const float* __restrict__ emb1,
                          const float* __restrict__ ii, const int* __restrict__ cntO,
                          const float* __restrict__ b1, __hip_bfloat16* __restrict__ h1) {
    __shared__ float wl[H1_NODES * VOCAB];
    __shared__ float sii[H1_NODES], soi[H1_NODES];
    int tid = threadIdx.x;
    if (blockIdx.x < EB) {
        int i = blockIdx.x * 256 + tid;
        if (i < N_EDGES) {
            int s = src[i], d = dst[i], v = feat[s];
            int slot = row_ptr[d] + (int)binbase[(size_t)d * VOCAB + v] + (int)rank8[i];
            col[slot] = s;
        }
        return;
    }
    int hb = blockIdx.x - EB;
    int j = tid & 127;
    int g = tid >> 7;
    float ev[VOCAB];
#pragma unroll
    for (int v = 0; v < VOCAB; ++v) ev[v] = emb1[v * H + j];
    float bj = b1[j];

    int node0 = hb * H1_NODES;
    int nn = min(H1_NODES, N_NODES - node0);
    const unsigned long long* wsrc = wc + (size_t)node0 * VOCAB;
    for (int i = tid; i < nn * VOCAB; i += 256) {
        unsigned long long p = wsrc[i];
        float lo = (float)((unsigned)p & 0xFFFFFFu);
        float hi = (float)((unsigned)(p >> 24) & 0xFFFFu);
        wl[i] = fmaf(lo, 1.0f / 16777216.0f, hi);
    }
    for (int i = tid; i < nn; i += 256) {
        sii[i] = ii[node0 + i];
        soi[i] = rsqrtf(fmaxf((float)cntO[node0 + i], 1.f));
    }
    __syncthreads();

    int rbeg = g * 32;
    int rend = min(rbeg + 32, nn);
    for (int r = rbeg; r < rend; ++r) {
        const float4* wr = (const float4*)(wl + r * VOCAB);
        float acc = 0.f;
#pragma unroll
        for (int q = 0; q < VOCAB / 4; ++q) {
            float4 w4 = wr[q];
            acc += w4.x * ev[4 * q] + w4.y * ev[4 * q + 1]
                 + w4.z * ev[4 * q + 2] + w4.w * ev[4 * q + 3];
        }
        float val = fmaxf(acc * sii[r] + bj, 0.f);
        h1[(size_t)(node0 + r) * H + j] = __float2bfloat16(val * soi[r]);
    }
}

// ---------------- layer 2 (fused): gather into LDS -> MFMA, 16-node tile ----------------
__global__ __launch_bounds__(256) void k_gather_mfma(
        const __hip_bfloat16* __restrict__ h,
        const int* __restrict__ row_ptr, const int* __restrict__ col,
        const __hip_bfloat16* __restrict__ WT,
        const float* __restrict__ ii, const float* __restrict__ b,
        float* __restrict__ outp, int n) {
    __shared__ __hip_bfloat16 sA[GM_NODES * SROW];
    int tid = threadIdx.x;
    int wave = tid >> 6;
    int lane = tid & 63;
    int l16 = lane & 15;
    int sub = lane >> 4;         // 0..3
    int co = l16 * 8;            // channel offset (8 bf16 = 16B per lane)
    int base = blockIdx.x * GM_NODES;

    // ---- gather phase: each wave gathers 4 nodes ----
    int local = wave * 4 + sub;
    int node = base + local;
    float a0 = 0.f, a1 = 0.f, a2 = 0.f, a3 = 0.f;
    float a4 = 0.f, a5 = 0.f, a6 = 0.f, a7 = 0.f;
    if (node < n) {
        int beg = row_ptr[node];
        int end = row_ptr[node + 1];
        int e = beg;
        for (; e + 8 <= end; e += 8) {
#pragma unroll
            for (int k = 0; k < 8; ++k) {
                int s = col[e + k];
                uint4 v = *(const uint4*)(h + (size_t)s * H + co);
                float2 f0 = __bfloat1622float2(*(__hip_bfloat162*)&v.x);
                float2 f1 = __bfloat1622float2(*(__hip_bfloat162*)&v.y);
                float2 f2 = __bfloat1622float2(*(__hip_bfloat162*)&v.z);
                float2 f3 = __bfloat1622float2(*(__hip_bfloat162*)&v.w);
                a0 += f0.x; a1 += f0.y; a2 += f1.x; a3 += f1.y;
                a4 += f2.x; a5 += f2.y; a6 += f3.x; a7 += f3.y;
            }
        }
        for (; e < end; ++e) {
            int s = col[e];
            uint4 v = *(const uint4*)(h + (size_t)s * H + co);
            float2 f0 = __bfloat1622float2(*(__hip_bfloat162*)&v.x);
            float2 f1 = __bfloat1622float2(*(__hip_bfloat162*)&v.y);
            float2 f2 = __bfloat1622float2(*(__hip_bfloat162*)&v.z);
            float2 f3 = __bfloat1622float2(*(__hip_bfloat162*)&v.w);
            a0 += f0.x; a1 += f0.y; a2 += f1.x; a3 += f1.y;
            a4 += f2.x; a5 += f2.y; a6 += f3.x; a7 += f3.y;
        }
    }
    __hip_bfloat162 o0 = __float22bfloat162_rn(make_float2(a0, a1));
    __hip_bfloat162 o1 = __float22bfloat162_rn(make_float2(a2, a3));
    __hip_bfloat162 o2 = __float22bfloat162_rn(make_float2(a4, a5));
    __hip_bfloat162 o3 = __float22bfloat162_rn(make_float2(a6, a7));
    uint4 ov;
    ov.x = *(unsigned*)&o0; ov.y = *(unsigned*)&o1;
    ov.z = *(unsigned*)&o2; ov.w = *(unsigned*)&o3;
    *(uint4*)(&sA[local * SROW + co]) = ov;
    __syncthreads();

    // ---- MFMA phase: wave handles col-tiles {2*wave, 2*wave+1} ----
    int rl = l16;
    int kg = sub;
    f4_t acc[2];
    acc[0] = f4_t{0.f, 0.f, 0.f, 0.f};
    acc[1] = f4_t{0.f, 0.f, 0.f, 0.f};
    const __hip_bfloat16* arow = &sA[rl * SROW + kg * 8];
#pragma unroll
    for (int ks = 0; ks < 4; ++ks) {
        bf8_t a = *(const bf8_t*)(arow + ks * 32);
#pragma unroll
        for (int t = 0; t < 2; ++t) {
            int ct = wave * 2 + t;
            bf8_t bf = *(const bf8_t*)(WT + (size_t)(ct * 16 + rl) * H + ks * 32 + kg * 8);
            acc[t] = __builtin_amdgcn_mfma_f32_16x16x32_bf16(a, bf, acc[t], 0, 0, 0);
        }
    }
    int rbase = base + kg * 4;
#pragma unroll
    for (int r = 0; r < 4; ++r) {
        int nd = rbase + r;
        if (nd < n) {
            float s = ii[nd];
#pragma unroll
            for (int t = 0; t < 2; ++t) {
                int c = (wave * 2 + t) * 16 + rl;
                float v = acc[t][r] * s + b[c];
                outp[(size_t)nd * H + c] = fmaxf(v, 0.f);
            }
        }
    }
}

// ---------------- pooling + first head GEMV (fused) ----------------
__global__ void k_poolmlp1(const float* __restrict__ h, const int* __restrict__ gid,
                           const float* __restrict__ e1w, const float* __restrict__ e1b,
                           float* __restrict__ t1, int n) {
    __shared__ int bnd[2];
    __shared__ float row[128];
    int g = blockIdx.x, t = threadIdx.x;
    if (t == 0) {
        int lo = 0, hi = n;
        while (lo < hi) { int m = (lo + hi) >> 1; if (gid[m] < g) lo = m + 1; else hi = m; }
        bnd[0] = lo;
        int lo2 = lo, hi2 = n;
        while (lo2 < hi2) { int m = (lo2 + hi2) >> 1; if (gid[m] < g + 1) lo2 = m + 1; else hi2 = m; }
        bnd[1] = lo2;
    }
    __syncthreads();
    int beg = bnd[0], end = bnd[1];
    float s = 0.f;
    for (int i = beg; i < end; ++i) s += h[(size_t)i * H + t];
    row[t] = s / fmaxf((float)(end - beg), 1.f);
    __syncthreads();
    float acc = e1b[t];
    for (int k = 0; k < H; ++k) acc += row[k] * e1w[k * H + t];
    t1[g * H + t] = acc;
}

// ---------------- BN stats / head ----------------
__global__ void k_bnstat(const float* __restrict__ x, float* __restrict__ stats, int G) {
    int c = blockIdx.x;
    float s = 0.f, s2 = 0.f;
    for (int g = threadIdx.x; g < G; g += blockDim.x) {
        float v = x[g * H + c];
        s += v; s2 += v * v;
    }
    __shared__ float rs[256], rs2[256];
    rs[threadIdx.x] = s; rs2[threadIdx.x] = s2;
    __syncthreads();
    for (int off = 128; off > 0; off >>= 1) {
        if (threadIdx.x < off) { rs[threadIdx.x] += rs[threadIdx.x + off]; rs2[threadIdx.x] += rs2[threadIdx.x + off]; }
        __syncthreads();
    }
    if (threadIdx.x == 0) {
        float mu = rs[0] / G;
        stats[c] = mu;
        stats[H + c] = rs2[0] / G - mu * mu;
    }
}

__global__ void k_mlp2bn(const float* __restrict__ t1, const float* __restrict__ stats,
                         const float* __restrict__ gam, const float* __restrict__ bet,
                         const float* __restrict__ W, const float* __restrict__ bias,
                         float* __restrict__ t2) {
    __shared__ float x[128];
    int g = blockIdx.x, t = threadIdx.x;
    float v = t1[g * H + t];
    v = (v - stats[t]) * rsqrtf(stats[H + t] + BN_EPS) * gam[t] + bet[t];
    x[t] = (v >= 0.f) ? v : 0.05f * v;
    __syncthreads();
    float acc = bias[t];
    for (int k = 0; k < H; ++k) acc += x[k] * W[k * H + t];
    t2[g * H + t] = acc;
}

__global__ void k_head(const float* __restrict__ t2, const float* __restrict__ stats,
                       const float* __restrict__ gam, const float* __restrict__ bet,
                       const float* __restrict__ e3w, const float* __restrict__ e3b,
                       const float* __restrict__ e4w, const float* __restrict__ e4b,
                       const float* __restrict__ e5w, const float* __restrict__ e5b,
                       float* __restrict__ out) {
    __shared__ float x[128], h3[64], h4[32];
    int g = blockIdx.x, t = threadIdx.x;
    float v = t2[g * H + t];
    v = (v - stats[t]) * rsqrtf(stats[H + t] + BN_EPS) * gam[t] + bet[t];
    x[t] = (v >= 0.f) ? v : 0.05f * v;
    __syncthreads();
    if (t < 64) {
        float a = e3b[t];
        for (int k = 0; k < 128; ++k) a += x[k] * e3w[k * 64 + t];
        h3[t] = (a >= 0.f) ? a : 0.1f * a;
    }
    __syncthreads();
    if (t < 32) {
        float a = e4b[t];
        for (int k = 0; k < 64; ++k) a += h3[k] * e4w[k * 32 + t];
        h4[t] = (a >= 0.f) ? a : 0.1f * a;
    }
    __syncthreads();
    if (t == 0) {
        float y0 = e5b[0], y1 = e5b[1];
        for (int k = 0; k < 32; ++k) {
            y0 += h4[k] * e5w[2 * k];
            y1 += h4[k] * e5w[2 * k + 1];
        }
        float m = fmaxf(y0, y1);
        float l = m + logf(expf(y0 - m) + expf(y1 - m));
        out[2 * g] = y0 - l;
        out[2 * g + 1] = y1 - l;
    }
}

extern "C" void kernel_launch(void* const* d_in, const int* in_sizes, int n_in,
                              void* d_out, int out_size, void* d_ws, size_t ws_size,
                              hipStream_t stream) {
    const int*   node_feat = (const int*)d_in[0];
    const int*   edge_src  = (const int*)d_in[1];
    const int*   edge_dst  = (const int*)d_in[2];
    const int*   graph_ids = (const int*)d_in[3];
    const float* emb  = (const float*)d_in[4];
    const float* W1   = (const float*)d_in[5];
    const float* b1   = (const float*)d_in[6];
    const float* W2   = (const float*)d_in[7];
    const float* b2   = (const float*)d_in[8];
    const float* e1_w = (const float*)d_in[9];
    const float* e1_b = (const float*)d_in[10];
    const float* e2_w = (const float*)d_in[11];
    const float* e2_b = (const float*)d_in[12];
    const float* e3_w = (const float*)d_in[13];
    const float* e3_b = (const float*)d_in[14];
    const float* e4_w = (const float*)d_in[15];
    const float* e4_b = (const float*)d_in[16];
    const float* e5_w = (const float*)d_in[17];
    const float* e5_b = (const float*)d_in[18];
    const float* bn0_g = (const float*)d_in[19];
    const float* bn0_b = (const float*)d_in[20];
    const float* bn1_g = (const float*)d_in[21];
    const float* bn1_b = (const float*)d_in[22];
    float* out = (float*)d_out;

    // workspace layout
    float* ws = (float*)d_ws;
    float* bufA = ws;                                                     // N*H f32 (h2)
    __hip_bfloat16* h1bf = (__hip_bfloat16*)(bufA + (size_t)N_NODES * H); // N*H bf16
    int*   cntO = (int*)(h1bf + (size_t)N_NODES * H);                     // 50000
    unsigned long long* wc = (unsigned long long*)(cntO + N_NODES);       // N*32 u64
    float* ii   = (float*)(wc + (size_t)N_NODES * VOCAB);
    int*   cntI = (int*)(ii + N_NODES);
    int*   row_ptr = cntI + N_NODES;                                      // 50001 -> pad 50048
    int*   col  = row_ptr + 50048;                                        // 600000
    unsigned char* binbase = (unsigned char*)(col + N_EDGES);             // N*32
    unsigned char* rank8   = binbase + (size_t)N_NODES * VOCAB;           // 600000
    float* t1   = (float*)(rank8 + ((N_EDGES + 63) & ~63));
    float* t2   = t1 + N_GRAPHS * H;
    float* stats = t2 + N_GRAPHS * H;                                     // 512
    int*   bsum  = (int*)(stats + 4 * H);                                 // 256
    float* emb1  = (float*)(bsum + 256);                                  // 4096
    __hip_bfloat16* w2t = (__hip_bfloat16*)(emb1 + VOCAB * H);            // 16384 bf16

    // zero cntO + wc with our own kernel (rocclr fill was 44 µs for 13 MB)
    k_zero<<<(ZERO_N16 + 255) / 256, 256, 0, stream>>>((uint4*)cntO, ZERO_N16);

    k_count_prep<<<EB + 160, 256, 0, stream>>>(edge_src, cntO, emb, W1, emb1, W2, w2t);
    k_hist64<<<EB, 256, 0, stream>>>(edge_src, edge_dst, node_feat, cntO, wc, rank8, N_EDGES);
    k_nodebins<<<SCAN_BLOCKS, 256, 0, stream>>>(wc, cntI, binbase, bsum, N_NODES);
    k_scatterscan<<<SCAN_BLOCKS, 256, 0, stream>>>(cntI, bsum, row_ptr, ii, N_NODES, SCAN_BLOCKS);
    k_fill_h1<<<EB + H1_BLOCKS, 256, 0, stream>>>(edge_src, edge_dst, node_feat, row_ptr,
                                                  binbase, rank8, col,
                                                  wc, emb1, ii, cntO, b1, h1bf);

    // layer 2: fused gather->LDS->MFMA (16-node tiles for occupancy)
    k_gather_mfma<<<(N_NODES + GM_NODES - 1) / GM_NODES, 256, 0, stream>>>(
        h1bf, row_ptr, col, w2t, ii, b2, bufA, N_NODES);

    // pooling + head
    k_poolmlp1<<<N_GRAPHS, 128, 0, stream>>>(bufA, graph_ids, e1_w, e1_b, t1, N_NODES);
    k_bnstat<<<H, 256, 0, stream>>>(t1, stats, N_GRAPHS);
    k_mlp2bn<<<N_GRAPHS, 128, 0, stream>>>(t1, stats, bn0_g, bn0_b, e2_w, e2_b, t2);
    k_bnstat<<<H, 256, 0, stream>>>(t2, stats + 2 * H, N_GRAPHS);
    k_head<<<N_GRAPHS, 128, 0, stream>>>(t2, stats + 2 * H, bn1_g, bn1_b,
                                         e3_w, e3_b, e4_w, e4_b, e5_w, e5_b, out);
}

// Round 15
// 204.107 us; speedup vs baseline: 1.0379x; 1.0379x over previous
//
#include <hip/hip_runtime.h>
#include <hip/hip_bf16.h>
#include <math.h>

#define N_NODES 50000
#define N_EDGES 600000
#define N_GRAPHS 1024
#define H 128
#define VOCAB 32
#define BN_EPS 1e-5f
#define SCAN_BLOCKS ((N_NODES + 255) / 256)   // 196
#define H1_NODES 64
#define EB ((N_EDGES + 255) / 256)            // 2344
#define GM_NODES 16
#define SROW 136
#define ZERO_BYTES (N_NODES * sizeof(int) + (size_t)N_NODES * VOCAB * 8)
#define ZERO_N16 ((int)(ZERO_BYTES / 16))

typedef short bf8_t __attribute__((ext_vector_type(8)));
typedef float f4_t __attribute__((ext_vector_type(4)));

// ---------------- pass 0: zero cntO + wc ----------------
__global__ void k_zero(uint4* __restrict__ p, int n16) {
    int i = blockIdx.x * blockDim.x + threadIdx.x;
    if (i < n16) p[i] = uint4{0u, 0u, 0u, 0u};
}

// ---------------- pass 1: out-degree count + weight prep (fused) ----------------
__global__ void k_count_prep(const int* __restrict__ src, int* __restrict__ cntO,
                             const float* __restrict__ emb, const float* __restrict__ W1,
                             float* __restrict__ emb1,
                             const float* __restrict__ W2, __hip_bfloat16* __restrict__ w2t) {
    int b = blockIdx.x;
    int t = threadIdx.x;
    if (b < EB) {
        int i = b * 256 + t;
        if (i < N_EDGES) atomicAdd(&cntO[src[i]], 1);
    } else if (b < EB + 32) {
        if (t < 128) {
            int v = b - EB;
            float acc = 0.f;
            for (int k = 0; k < H; ++k) acc += emb[v * H + k] * W1[k * H + t];
            emb1[v * H + t] = acc;
        }
    } else {
        if (t < 128) {
            int k = b - EB - 32;
            w2t[(size_t)t * H + k] = __float2bfloat16(W2[(size_t)k * H + t]);
        }
    }
}

// ---------------- pass 2: fused weighted histogram + in-degree (64-bit atomics) ----------------
__global__ void k_hist64(const int* __restrict__ src, const int* __restrict__ dst,
                         const int* __restrict__ feat, const int* __restrict__ cntO,
                         unsigned long long* __restrict__ wc,
                         unsigned char* __restrict__ rank8, int E) {
    int i = blockIdx.x * blockDim.x + threadIdx.x;
    if (i >= E) return;
    int s = src[i], d = dst[i], v = feat[s];
    float o = rsqrtf(fmaxf((float)cntO[s], 1.f));
    unsigned long long q = (unsigned long long)__float2uint_rn(o * 16777216.0f);
    unsigned long long old = atomicAdd(&wc[(size_t)d * VOCAB + v], (1ULL << 40) | q);
    rank8[i] = (unsigned char)(old >> 40);
}

// ---------------- pass 3: per-node bin scan + cntI + per-256-node block sums ----------------
__global__ void k_nodebins(const unsigned long long* __restrict__ wc,
                           int* __restrict__ cntI, unsigned char* __restrict__ binbase,
                           int* __restrict__ bsum, int n) {
    __shared__ int scnt[256];
    int t = threadIdx.x;
    int wave = t >> 6, lane = t & 63;
    int sub = lane >> 5;
    int l32 = lane & 31;
    int nodeBase = blockIdx.x * 256;
#pragma unroll 4
    for (int it = 0; it < 32; ++it) {
        int local = wave * 64 + it * 2 + sub;
        int node = nodeBase + local;
        int c = 0;
        if (node < n && l32 < VOCAB)
            c = (int)(wc[(size_t)node * VOCAB + l32] >> 40);
        int inc = c;
#pragma unroll
        for (int off = 1; off < VOCAB; off <<= 1) {
            int u = __shfl_up(inc, off, 32);
            if (l32 >= off) inc += u;
        }
        if (node < n && l32 < VOCAB)
            binbase[(size_t)node * VOCAB + l32] = (unsigned char)(inc - c);
        if (l32 == VOCAB - 1) scnt[local] = (node < n) ? inc : 0;
    }
    __syncthreads();
    int node = nodeBase + t;
    if (node < n) cntI[node] = scnt[t];
    __shared__ int red[256];
    red[t] = scnt[t];
    __syncthreads();
    for (int off = 128; off > 0; off >>= 1) {
        if (t < off) red[t] += red[t + off];
        __syncthreads();
    }
    if (t == 0) bsum[blockIdx.x] = red[0];
}

// ---------------- pass 4: scatter-scan with inline (redundant) bsum scan ----------------
__global__ void k_scatterscan(const int* __restrict__ cntI, const int* __restrict__ bsum,
                              int* __restrict__ row_ptr, float* __restrict__ ii,
                              int n, int nb) {
    __shared__ int sb[256];
    __shared__ int sh[256];
    int t = threadIdx.x;
    int bv = (t < nb) ? bsum[t] : 0;
    sb[t] = bv;
    __syncthreads();
    for (int off = 1; off < 256; off <<= 1) {
        int u = (t >= off) ? sb[t - off] : 0;
        __syncthreads();
        sb[t] += u;
        __syncthreads();
    }
    int blockoff = (blockIdx.x == 0) ? 0 : sb[blockIdx.x - 1];
    int i = blockIdx.x * 256 + t;
    int v = (i < n) ? cntI[i] : 0;
    sh[t] = v;
    __syncthreads();
    for (int off = 1; off < 256; off <<= 1) {
        int u = (t >= off) ? sh[t - off] : 0;
        __syncthreads();
        sh[t] += u;
        __syncthreads();
    }
    if (i < n) {
        row_ptr[i] = blockoff + sh[t] - v;
        ii[i] = rsqrtf(fmaxf((float)v, 1.f));
    }
    if (blockIdx.x == 0 && t == 0) row_ptr[n] = sb[nb - 1];
}

// ---------------- pass 5 (fused): atomic-free CSR fill + layer-1 h1 compute ----------------
#define H1_BLOCKS ((N_NODES + H1_NODES - 1) / H1_NODES)   // 782
__global__ void k_fill_h1(const int* __restrict__ src, const int* __restrict__ dst,
                          const int* __restrict__ feat, const int* __restrict__ row_ptr,
                          const unsigned char* __restrict__ binbase,
                          const unsigned char* __restrict__ rank8,
                          int* __restrict__ col,
                          const unsigned long long* __restrict__ wc,
                          const float* __restrict__ emb1,
                          const float* __restrict__ ii, const int* __restrict__ cntO,
                          const float* __restrict__ b1, __hip_bfloat16* __restrict__ h1) {
    __shared__ float wl[H1_NODES * VOCAB];
    __shared__ float sii[H1_NODES], soi[H1_NODES];
    int tid = threadIdx.x;
    if (blockIdx.x < EB) {
        int i = blockIdx.x * 256 + tid;
        if (i < N_EDGES) {
            int s = src[i], d = dst[i], v = feat[s];
            int slot = row_ptr[d] + (int)binbase[(size_t)d * VOCAB + v] + (int)rank8[i];
            col[slot] = s;
        }
        return;
    }
    int hb = blockIdx.x - EB;
    int j = tid & 127;
    int g = tid >> 7;
    float ev[VOCAB];
#pragma unroll
    for (int v = 0; v < VOCAB; ++v) ev[v] = emb1[v * H + j];
    float bj = b1[j];

    int node0 = hb * H1_NODES;
    int nn = min(H1_NODES, N_NODES - node0);
    const unsigned long long* wsrc = wc + (size_t)node0 * VOCAB;
    for (int i = tid; i < nn * VOCAB; i += 256) {
        unsigned long long p = wsrc[i];
        float lo = (float)((unsigned)p & 0xFFFFFFu);
        float hi = (float)((unsigned)(p >> 24) & 0xFFFFu);
        wl[i] = fmaf(lo, 1.0f / 16777216.0f, hi);
    }
    for (int i = tid; i < nn; i += 256) {
        sii[i] = ii[node0 + i];
        soi[i] = rsqrtf(fmaxf((float)cntO[node0 + i], 1.f));
    }
    __syncthreads();

    int rbeg = g * 32;
    int rend = min(rbeg + 32, nn);
    for (int r = rbeg; r < rend; ++r) {
        const float4* wr = (const float4*)(wl + r * VOCAB);
        float acc = 0.f;
#pragma unroll
        for (int q = 0; q < VOCAB / 4; ++q) {
            float4 w4 = wr[q];
            acc += w4.x * ev[4 * q] + w4.y * ev[4 * q + 1]
                 + w4.z * ev[4 * q + 2] + w4.w * ev[4 * q + 3];
        }
        float val = fmaxf(acc * sii[r] + bj, 0.f);
        h1[(size_t)(node0 + r) * H + j] = __float2bfloat16(val * soi[r]);
    }
}

// ---------------- layer 2 (fused): gather into LDS -> MFMA, 16-node tile ----------------
// Gather uses explicit 8-deep register staging (s[8]/v[8] fully unrolled -> VGPRs)
// so 8 row loads stay in flight; tail handled as one masked 8-batch.
__global__ __launch_bounds__(256) void k_gather_mfma(
        const __hip_bfloat16* __restrict__ h,
        const int* __restrict__ row_ptr, const int* __restrict__ col,
        const __hip_bfloat16* __restrict__ WT,
        const float* __restrict__ ii, const float* __restrict__ b,
        __hip_bfloat16* __restrict__ outp, int n) {
    __shared__ __hip_bfloat16 sA[GM_NODES * SROW];
    int tid = threadIdx.x;
    int wave = tid >> 6;
    int lane = tid & 63;
    int l16 = lane & 15;
    int sub = lane >> 4;         // 0..3
    int co = l16 * 8;            // channel offset (8 bf16 = 16B per lane)
    int base = blockIdx.x * GM_NODES;

    // ---- gather phase ----
    int local = wave * 4 + sub;
    int node = base + local;
    float a0 = 0.f, a1 = 0.f, a2 = 0.f, a3 = 0.f;
    float a4 = 0.f, a5 = 0.f, a6 = 0.f, a7 = 0.f;
    if (node < n) {
        int beg = row_ptr[node];
        int end = row_ptr[node + 1];
        int e = beg;
        for (; e + 8 <= end; e += 8) {
            int s[8];
            uint4 v[8];
#pragma unroll
            for (int k = 0; k < 8; ++k) s[k] = col[e + k];
#pragma unroll
            for (int k = 0; k < 8; ++k)
                v[k] = *(const uint4*)(h + (size_t)s[k] * H + co);
#pragma unroll
            for (int k = 0; k < 8; ++k) {
                float2 f0 = __bfloat1622float2(*(__hip_bfloat162*)&v[k].x);
                float2 f1 = __bfloat1622float2(*(__hip_bfloat162*)&v[k].y);
                float2 f2 = __bfloat1622float2(*(__hip_bfloat162*)&v[k].z);
                float2 f3 = __bfloat1622float2(*(__hip_bfloat162*)&v[k].w);
                a0 += f0.x; a1 += f0.y; a2 += f1.x; a3 += f1.y;
                a4 += f2.x; a5 += f2.y; a6 += f3.x; a7 += f3.y;
            }
        }
        if (e < end) {
            int s[8];
            uint4 v[8];
            float m[8];
#pragma unroll
            for (int k = 0; k < 8; ++k) {
                int idx = (e + k < end) ? e + k : e;
                s[k] = col[idx];
                m[k] = (e + k < end) ? 1.f : 0.f;
            }
#pragma unroll
            for (int k = 0; k < 8; ++k)
                v[k] = *(const uint4*)(h + (size_t)s[k] * H + co);
#pragma unroll
            for (int k = 0; k < 8; ++k) {
                float2 f0 = __bfloat1622float2(*(__hip_bfloat162*)&v[k].x);
                float2 f1 = __bfloat1622float2(*(__hip_bfloat162*)&v[k].y);
                float2 f2 = __bfloat1622float2(*(__hip_bfloat162*)&v[k].z);
                float2 f3 = __bfloat1622float2(*(__hip_bfloat162*)&v[k].w);
                a0 += m[k] * f0.x; a1 += m[k] * f0.y; a2 += m[k] * f1.x; a3 += m[k] * f1.y;
                a4 += m[k] * f2.x; a5 += m[k] * f2.y; a6 += m[k] * f3.x; a7 += m[k] * f3.y;
            }
        }
    }
    __hip_bfloat162 o0 = __float22bfloat162_rn(make_float2(a0, a1));
    __hip_bfloat162 o1 = __float22bfloat162_rn(make_float2(a2, a3));
    __hip_bfloat162 o2 = __float22bfloat162_rn(make_float2(a4, a5));
    __hip_bfloat162 o3 = __float22bfloat162_rn(make_float2(a6, a7));
    uint4 ov;
    ov.x = *(unsigned*)&o0; ov.y = *(unsigned*)&o1;
    ov.z = *(unsigned*)&o2; ov.w = *(unsigned*)&o3;
    *(uint4*)(&sA[local * SROW + co]) = ov;
    __syncthreads();

    // ---- MFMA phase: wave handles col-tiles {2*wave, 2*wave+1} ----
    int rl = l16;
    int kg = sub;
    f4_t acc[2];
    acc[0] = f4_t{0.f, 0.f, 0.f, 0.f};
    acc[1] = f4_t{0.f, 0.f, 0.f, 0.f};
    const __hip_bfloat16* arow = &sA[rl * SROW + kg * 8];
#pragma unroll
    for (int ks = 0; ks < 4; ++ks) {
        bf8_t a = *(const bf8_t*)(arow + ks * 32);
#pragma unroll
        for (int t = 0; t < 2; ++t) {
            int ct = wave * 2 + t;
            bf8_t bf = *(const bf8_t*)(WT + (size_t)(ct * 16 + rl) * H + ks * 32 + kg * 8);
            acc[t] = __builtin_amdgcn_mfma_f32_16x16x32_bf16(a, bf, acc[t], 0, 0, 0);
        }
    }
    int rbase = base + kg * 4;
#pragma unroll
    for (int r = 0; r < 4; ++r) {
        int nd = rbase + r;
        if (nd < n) {
            float s = ii[nd];
#pragma unroll
            for (int t = 0; t < 2; ++t) {
                int c = (wave * 2 + t) * 16 + rl;
                float v = acc[t][r] * s + b[c];
                outp[(size_t)nd * H + c] = __float2bfloat16(fmaxf(v, 0.f));
            }
        }
    }
}

// ---------------- pooling + first head GEMV (fused), bf16 h2 input ----------------
__global__ void k_poolmlp1(const __hip_bfloat16* __restrict__ h, const int* __restrict__ gid,
                           const float* __restrict__ e1w, const float* __restrict__ e1b,
                           float* __restrict__ t1, int n) {
    __shared__ int bnd[2];
    __shared__ float row[128];
    int g = blockIdx.x, t = threadIdx.x;
    if (t == 0) {
        int lo = 0, hi = n;
        while (lo < hi) { int m = (lo + hi) >> 1; if (gid[m] < g) lo = m + 1; else hi = m; }
        bnd[0] = lo;
        int lo2 = lo, hi2 = n;
        while (lo2 < hi2) { int m = (lo2 + hi2) >> 1; if (gid[m] < g + 1) lo2 = m + 1; else hi2 = m; }
        bnd[1] = lo2;
    }
    __syncthreads();
    int beg = bnd[0], end = bnd[1];
    float s = 0.f;
    for (int i = beg; i < end; ++i) s += __bfloat162float(h[(size_t)i * H + t]);
    row[t] = s / fmaxf((float)(end - beg), 1.f);
    __syncthreads();
    float acc = e1b[t];
    for (int k = 0; k < H; ++k) acc += row[k] * e1w[k * H + t];
    t1[g * H + t] = acc;
}

// ---------------- BN stats / head ----------------
__global__ void k_bnstat(const float* __restrict__ x, float* __restrict__ stats, int G) {
    int c = blockIdx.x;
    float s = 0.f, s2 = 0.f;
    for (int g = threadIdx.x; g < G; g += blockDim.x) {
        float v = x[g * H + c];
        s += v; s2 += v * v;
    }
    __shared__ float rs[256], rs2[256];
    rs[threadIdx.x] = s; rs2[threadIdx.x] = s2;
    __syncthreads();
    for (int off = 128; off > 0; off >>= 1) {
        if (threadIdx.x < off) { rs[threadIdx.x] += rs[threadIdx.x + off]; rs2[threadIdx.x] += rs2[threadIdx.x + off]; }
        __syncthreads();
    }
    if (threadIdx.x == 0) {
        float mu = rs[0] / G;
        stats[c] = mu;
        stats[H + c] = rs2[0] / G - mu * mu;
    }
}

__global__ void k_mlp2bn(const float* __restrict__ t1, const float* __restrict__ stats,
                         const float* __restrict__ gam, const float* __restrict__ bet,
                         const float* __restrict__ W, const float* __restrict__ bias,
                         float* __restrict__ t2) {
    __shared__ float x[128];
    int g = blockIdx.x, t = threadIdx.x;
    float v = t1[g * H + t];
    v = (v - stats[t]) * rsqrtf(stats[H + t] + BN_EPS) * gam[t] + bet[t];
    x[t] = (v >= 0.f) ? v : 0.05f * v;
    __syncthreads();
    float acc = bias[t];
    for (int k = 0; k < H; ++k) acc += x[k] * W[k * H + t];
    t2[g * H + t] = acc;
}

__global__ void k_head(const float* __restrict__ t2, const float* __restrict__ stats,
                       const float* __restrict__ gam, const float* __restrict__ bet,
                       const float* __restrict__ e3w, const float* __restrict__ e3b,
                       const float* __restrict__ e4w, const float* __restrict__ e4b,
                       const float* __restrict__ e5w, const float* __restrict__ e5b,
                       float* __restrict__ out) {
    __shared__ float x[128], h3[64], h4[32];
    int g = blockIdx.x, t = threadIdx.x;
    float v = t2[g * H + t];
    v = (v - stats[t]) * rsqrtf(stats[H + t] + BN_EPS) * gam[t] + bet[t];
    x[t] = (v >= 0.f) ? v : 0.05f * v;
    __syncthreads();
    if (t < 64) {
        float a = e3b[t];
        for (int k = 0; k < 128; ++k) a += x[k] * e3w[k * 64 + t];
        h3[t] = (a >= 0.f) ? a : 0.1f * a;
    }
    __syncthreads();
    if (t < 32) {
        float a = e4b[t];
        for (int k = 0; k < 64; ++k) a += h3[k] * e4w[k * 32 + t];
        h4[t] = (a >= 0.f) ? a : 0.1f * a;
    }
    __syncthreads();
    if (t == 0) {
        float y0 = e5b[0], y1 = e5b[1];
        for (int k = 0; k < 32; ++k) {
            y0 += h4[k] * e5w[2 * k];
            y1 += h4[k] * e5w[2 * k + 1];
        }
        float m = fmaxf(y0, y1);
        float l = m + logf(expf(y0 - m) + expf(y1 - m));
        out[2 * g] = y0 - l;
        out[2 * g + 1] = y1 - l;
    }
}

extern "C" void kernel_launch(void* const* d_in, const int* in_sizes, int n_in,
                              void* d_out, int out_size, void* d_ws, size_t ws_size,
                              hipStream_t stream) {
    const int*   node_feat = (const int*)d_in[0];
    const int*   edge_src  = (const int*)d_in[1];
    const int*   edge_dst  = (const int*)d_in[2];
    const int*   graph_ids = (const int*)d_in[3];
    const float* emb  = (const float*)d_in[4];
    const float* W1   = (const float*)d_in[5];
    const float* b1   = (const float*)d_in[6];
    const float* W2   = (const float*)d_in[7];
    const float* b2   = (const float*)d_in[8];
    const float* e1_w = (const float*)d_in[9];
    const float* e1_b = (const float*)d_in[10];
    const float* e2_w = (const float*)d_in[11];
    const float* e2_b = (const float*)d_in[12];
    const float* e3_w = (const float*)d_in[13];
    const float* e3_b = (const float*)d_in[14];
    const float* e4_w = (const float*)d_in[15];
    const float* e4_b = (const float*)d_in[16];
    const float* e5_w = (const float*)d_in[17];
    const float* e5_b = (const float*)d_in[18];
    const float* bn0_g = (const float*)d_in[19];
    const float* bn0_b = (const float*)d_in[20];
    const float* bn1_g = (const float*)d_in[21];
    const float* bn1_b = (const float*)d_in[22];
    float* out = (float*)d_out;

    // workspace layout
    float* ws = (float*)d_ws;
    float* bufA = ws;                                                     // h2 (bf16, reuses f32 slot)
    __hip_bfloat16* h2bf = (__hip_bfloat16*)bufA;
    __hip_bfloat16* h1bf = (__hip_bfloat16*)(bufA + (size_t)N_NODES * H); // N*H bf16
    int*   cntO = (int*)(h1bf + (size_t)N_NODES * H);                     // 50000
    unsigned long long* wc = (unsigned long long*)(cntO + N_NODES);       // N*32 u64
    float* ii   = (float*)(wc + (size_t)N_NODES * VOCAB);
    int*   cntI = (int*)(ii + N_NODES);
    int*   row_ptr = cntI + N_NODES;                                      // 50001 -> pad 50048
    int*   col  = row_ptr + 50048;                                        // 600000
    unsigned char* binbase = (unsigned char*)(col + N_EDGES);             // N*32
    unsigned char* rank8   = binbase + (size_t)N_NODES * VOCAB;           // 600000
    float* t1   = (float*)(rank8 + ((N_EDGES + 63) & ~63));
    float* t2   = t1 + N_GRAPHS * H;
    float* stats = t2 + N_GRAPHS * H;                                     // 512
    int*   bsum  = (int*)(stats + 4 * H);                                 // 256
    float* emb1  = (float*)(bsum + 256);                                  // 4096
    __hip_bfloat16* w2t = (__hip_bfloat16*)(emb1 + VOCAB * H);            // 16384 bf16

    // zero cntO + wc with our own kernel
    k_zero<<<(ZERO_N16 + 255) / 256, 256, 0, stream>>>((uint4*)cntO, ZERO_N16);

    k_count_prep<<<EB + 160, 256, 0, stream>>>(edge_src, cntO, emb, W1, emb1, W2, w2t);
    k_hist64<<<EB, 256, 0, stream>>>(edge_src, edge_dst, node_feat, cntO, wc, rank8, N_EDGES);
    k_nodebins<<<SCAN_BLOCKS, 256, 0, stream>>>(wc, cntI, binbase, bsum, N_NODES);
    k_scatterscan<<<SCAN_BLOCKS, 256, 0, stream>>>(cntI, bsum, row_ptr, ii, N_NODES, SCAN_BLOCKS);
    k_fill_h1<<<EB + H1_BLOCKS, 256, 0, stream>>>(edge_src, edge_dst, node_feat, row_ptr,
                                                  binbase, rank8, col,
                                                  wc, emb1, ii, cntO, b1, h1bf);

    // layer 2: fused gather->LDS->MFMA (register-staged gather), bf16 h2 out
    k_gather_mfma<<<(N_NODES + GM_NODES - 1) / GM_NODES, 256, 0, stream>>>(
        h1bf, row_ptr, col, w2t, ii, b2, h2bf, N_NODES);

    // pooling + head
    k_poolmlp1<<<N_GRAPHS, 128, 0, stream>>>(h2bf, graph_ids, e1_w, e1_b, t1, N_NODES);
    k_bnstat<<<H, 256, 0, stream>>>(t1, stats, N_GRAPHS);
    k_mlp2bn<<<N_GRAPHS, 128, 0, stream>>>(t1, stats, bn0_g, bn0_b, e2_w, e2_b, t2);
    k_bnstat<<<H, 256, 0, stream>>>(t2, stats + 2 * H, N_GRAPHS);
    k_head<<<N_GRAPHS, 128, 0, stream>>>(t2, stats + 2 * H, bn1_g, bn1_b,
                                         e3_w, e3_b, e4_w, e4_b, e5_w, e5_b, out);
}

// Round 16
// 203.559 us; speedup vs baseline: 1.0407x; 1.0027x over previous
//
#include <hip/hip_runtime.h>
#include <hip/hip_bf16.h>
#include <math.h>

#define N_NODES 50000
#define N_EDGES 600000
#define N_GRAPHS 1024
#define H 128
#define VOCAB 32
#define BN_EPS 1e-5f
#define SCAN_BLOCKS ((N_NODES + 255) / 256)   // 196
#define H1_NODES 64
#define EB ((N_EDGES + 255) / 256)            // 2344
#define GM_NODES 16
#define SROW 136
// cntO (50000 int) + wc32 (N*32 u32) contiguous = 6.6 MB
#define ZERO_BYTES ((size_t)N_NODES * 4 + (size_t)N_NODES * VOCAB * 4)
#define ZERO_N16 ((int)(ZERO_BYTES / 16))

typedef short bf8_t __attribute__((ext_vector_type(8)));
typedef float f4_t __attribute__((ext_vector_type(4)));

// ---------------- pass 0: zero cntO + wc32 ----------------
__global__ void k_zero(uint4* __restrict__ p, int n16) {
    int i = blockIdx.x * blockDim.x + threadIdx.x;
    if (i < n16) p[i] = uint4{0u, 0u, 0u, 0u};
}

// ---------------- pass 1: out-degree count + weight prep (fused) ----------------
__global__ void k_count_prep(const int* __restrict__ src, int* __restrict__ cntO,
                             const float* __restrict__ emb, const float* __restrict__ W1,
                             float* __restrict__ emb1,
                             const float* __restrict__ W2, __hip_bfloat16* __restrict__ w2t) {
    int b = blockIdx.x;
    int t = threadIdx.x;
    if (b < EB) {
        int i = b * 256 + t;
        if (i < N_EDGES) atomicAdd(&cntO[src[i]], 1);
    } else if (b < EB + 32) {
        if (t < 128) {
            int v = b - EB;
            float acc = 0.f;
            for (int k = 0; k < H; ++k) acc += emb[v * H + k] * W1[k * H + t];
            emb1[v * H + t] = acc;
        }
    } else {
        if (t < 128) {
            int k = b - EB - 32;
            w2t[(size_t)t * H + k] = __float2bfloat16(W2[(size_t)k * H + t]);
        }
    }
}

// ---------------- pass 2: fused weighted histogram + in-degree (u32 atomics) ----------
// wc32[d][v] = (count << 27) | sum(round(oi * 2^20));  count<=31 (P(overflow)~1e-40)
__global__ void k_hist32(const int* __restrict__ src, const int* __restrict__ dst,
                         const int* __restrict__ feat, const int* __restrict__ cntO,
                         unsigned* __restrict__ wc,
                         unsigned char* __restrict__ rank8, int E) {
    int i = blockIdx.x * blockDim.x + threadIdx.x;
    if (i >= E) return;
    int s = src[i], d = dst[i], v = feat[s];
    float o = rsqrtf(fmaxf((float)cntO[s], 1.f));
    unsigned q = __float2uint_rn(o * 1048576.0f);   // 2^20 fixpoint, <= 2^20
    unsigned old = atomicAdd(&wc[(size_t)d * VOCAB + v], (1u << 27) | q);
    rank8[i] = (unsigned char)(old >> 27);
}

// ---------------- pass 3: per-node bin scan + cntI + per-256-node block sums ----------------
__global__ void k_nodebins(const unsigned* __restrict__ wc,
                           int* __restrict__ cntI, unsigned char* __restrict__ binbase,
                           int* __restrict__ bsum, int n) {
    __shared__ int scnt[256];
    int t = threadIdx.x;
    int wave = t >> 6, lane = t & 63;
    int sub = lane >> 5;
    int l32 = lane & 31;
    int nodeBase = blockIdx.x * 256;
#pragma unroll 4
    for (int it = 0; it < 32; ++it) {
        int local = wave * 64 + it * 2 + sub;
        int node = nodeBase + local;
        int c = 0;
        if (node < n && l32 < VOCAB)
            c = (int)(wc[(size_t)node * VOCAB + l32] >> 27);
        int inc = c;
#pragma unroll
        for (int off = 1; off < VOCAB; off <<= 1) {
            int u = __shfl_up(inc, off, 32);
            if (l32 >= off) inc += u;
        }
        if (node < n && l32 < VOCAB)
            binbase[(size_t)node * VOCAB + l32] = (unsigned char)(inc - c);
        if (l32 == VOCAB - 1) scnt[local] = (node < n) ? inc : 0;
    }
    __syncthreads();
    int node = nodeBase + t;
    if (node < n) cntI[node] = scnt[t];
    __shared__ int red[256];
    red[t] = scnt[t];
    __syncthreads();
    for (int off = 128; off > 0; off >>= 1) {
        if (t < off) red[t] += red[t + off];
        __syncthreads();
    }
    if (t == 0) bsum[blockIdx.x] = red[0];
}

// ---------------- pass 4: scatter-scan with inline (redundant) bsum scan ----------------
__global__ void k_scatterscan(const int* __restrict__ cntI, const int* __restrict__ bsum,
                              int* __restrict__ row_ptr, float* __restrict__ ii,
                              int n, int nb) {
    __shared__ int sb[256];
    __shared__ int sh[256];
    int t = threadIdx.x;
    int bv = (t < nb) ? bsum[t] : 0;
    sb[t] = bv;
    __syncthreads();
    for (int off = 1; off < 256; off <<= 1) {
        int u = (t >= off) ? sb[t - off] : 0;
        __syncthreads();
        sb[t] += u;
        __syncthreads();
    }
    int blockoff = (blockIdx.x == 0) ? 0 : sb[blockIdx.x - 1];
    int i = blockIdx.x * 256 + t;
    int v = (i < n) ? cntI[i] : 0;
    sh[t] = v;
    __syncthreads();
    for (int off = 1; off < 256; off <<= 1) {
        int u = (t >= off) ? sh[t - off] : 0;
        __syncthreads();
        sh[t] += u;
        __syncthreads();
    }
    if (i < n) {
        row_ptr[i] = blockoff + sh[t] - v;
        ii[i] = rsqrtf(fmaxf((float)v, 1.f));
    }
    if (blockIdx.x == 0 && t == 0) row_ptr[n] = sb[nb - 1];
}

// ---------------- pass 5 (fused): atomic-free CSR fill + layer-1 h1 compute ----------------
#define H1_BLOCKS ((N_NODES + H1_NODES - 1) / H1_NODES)   // 782
__global__ void k_fill_h1(const int* __restrict__ src, const int* __restrict__ dst,
                          const int* __restrict__ feat, const int* __restrict__ row_ptr,
                          const unsigned char* __restrict__ binbase,
                          const unsigned char* __restrict__ rank8,
                          int* __restrict__ col,
                          const unsigned* __restrict__ wc,
                          const float* __restrict__ emb1,
                          const float* __restrict__ ii, const int* __restrict__ cntO,
                          const float* __restrict__ b1, __hip_bfloat16* __restrict__ h1) {
    __shared__ float wl[H1_NODES * VOCAB];
    __shared__ float sii[H1_NODES], soi[H1_NODES];
    int tid = threadIdx.x;
    if (blockIdx.x < EB) {
        int i = blockIdx.x * 256 + tid;
        if (i < N_EDGES) {
            int s = src[i], d = dst[i], v = feat[s];
            int slot = row_ptr[d] + (int)binbase[(size_t)d * VOCAB + v] + (int)rank8[i];
            col[slot] = s;
        }
        return;
    }
    int hb = blockIdx.x - EB;
    int j = tid & 127;
    int g = tid >> 7;
    float ev[VOCAB];
#pragma unroll
    for (int v = 0; v < VOCAB; ++v) ev[v] = emb1[v * H + j];
    float bj = b1[j];

    int node0 = hb * H1_NODES;
    int nn = min(H1_NODES, N_NODES - node0);
    const unsigned* wsrc = wc + (size_t)node0 * VOCAB;
    for (int i = tid; i < nn * VOCAB; i += 256) {
        unsigned p = wsrc[i];
        wl[i] = (float)(p & 0x07FFFFFFu) * (1.0f / 1048576.0f);
    }
    for (int i = tid; i < nn; i += 256) {
        sii[i] = ii[node0 + i];
        soi[i] = rsqrtf(fmaxf((float)cntO[node0 + i], 1.f));
    }
    __syncthreads();

    int rbeg = g * 32;
    int rend = min(rbeg + 32, nn);
    for (int r = rbeg; r < rend; ++r) {
        const float4* wr = (const float4*)(wl + r * VOCAB);
        float acc = 0.f;
#pragma unroll
        for (int q = 0; q < VOCAB / 4; ++q) {
            float4 w4 = wr[q];
            acc += w4.x * ev[4 * q] + w4.y * ev[4 * q + 1]
                 + w4.z * ev[4 * q + 2] + w4.w * ev[4 * q + 3];
        }
        float val = fmaxf(acc * sii[r] + bj, 0.f);
        h1[(size_t)(node0 + r) * H + j] = __float2bfloat16(val * soi[r]);
    }
}

// ---------------- layer 2 (fused): gather into LDS -> MFMA, 16-node tile ----------------
// Gather: 16-deep register-staged batches (one unmasked loop + one masked tail)
// -> ~1.2 latency exposures per node vs 1.9 at 8-deep.
__global__ __launch_bounds__(256) void k_gather_mfma(
        const __hip_bfloat16* __restrict__ h,
        const int* __restrict__ row_ptr, const int* __restrict__ col,
        const __hip_bfloat16* __restrict__ WT,
        const float* __restrict__ ii, const float* __restrict__ b,
        __hip_bfloat16* __restrict__ outp, int n) {
    __shared__ __hip_bfloat16 sA[GM_NODES * SROW];
    int tid = threadIdx.x;
    int wave = tid >> 6;
    int lane = tid & 63;
    int l16 = lane & 15;
    int sub = lane >> 4;         // 0..3
    int co = l16 * 8;            // channel offset (8 bf16 = 16B per lane)
    int base = blockIdx.x * GM_NODES;

    // ---- gather phase ----
    int local = wave * 4 + sub;
    int node = base + local;
    float a0 = 0.f, a1 = 0.f, a2 = 0.f, a3 = 0.f;
    float a4 = 0.f, a5 = 0.f, a6 = 0.f, a7 = 0.f;
    if (node < n) {
        int beg = row_ptr[node];
        int end = row_ptr[node + 1];
        int e = beg;
        for (; e + 16 <= end; e += 16) {
            int s[16];
            uint4 v[16];
#pragma unroll
            for (int k = 0; k < 16; ++k) s[k] = col[e + k];
#pragma unroll
            for (int k = 0; k < 16; ++k)
                v[k] = *(const uint4*)(h + (size_t)s[k] * H + co);
#pragma unroll
            for (int k = 0; k < 16; ++k) {
                float2 f0 = __bfloat1622float2(*(__hip_bfloat162*)&v[k].x);
                float2 f1 = __bfloat1622float2(*(__hip_bfloat162*)&v[k].y);
                float2 f2 = __bfloat1622float2(*(__hip_bfloat162*)&v[k].z);
                float2 f3 = __bfloat1622float2(*(__hip_bfloat162*)&v[k].w);
                a0 += f0.x; a1 += f0.y; a2 += f1.x; a3 += f1.y;
                a4 += f2.x; a5 += f2.y; a6 += f3.x; a7 += f3.y;
            }
        }
        if (e < end) {
            int s[16];
            uint4 v[16];
#pragma unroll
            for (int k = 0; k < 16; ++k) s[k] = col[(e + k < end) ? e + k : e];
#pragma unroll
            for (int k = 0; k < 16; ++k)
                v[k] = *(const uint4*)(h + (size_t)s[k] * H + co);
#pragma unroll
            for (int k = 0; k < 16; ++k) {
                float mk = (e + k < end) ? 1.f : 0.f;
                float2 f0 = __bfloat1622float2(*(__hip_bfloat162*)&v[k].x);
                float2 f1 = __bfloat1622float2(*(__hip_bfloat162*)&v[k].y);
                float2 f2 = __bfloat1622float2(*(__hip_bfloat162*)&v[k].z);
                float2 f3 = __bfloat1622float2(*(__hip_bfloat162*)&v[k].w);
                a0 += mk * f0.x; a1 += mk * f0.y; a2 += mk * f1.x; a3 += mk * f1.y;
                a4 += mk * f2.x; a5 += mk * f2.y; a6 += mk * f3.x; a7 += mk * f3.y;
            }
        }
    }
    __hip_bfloat162 o0 = __float22bfloat162_rn(make_float2(a0, a1));
    __hip_bfloat162 o1 = __float22bfloat162_rn(make_float2(a2, a3));
    __hip_bfloat162 o2 = __float22bfloat162_rn(make_float2(a4, a5));
    __hip_bfloat162 o3 = __float22bfloat162_rn(make_float2(a6, a7));
    uint4 ov;
    ov.x = *(unsigned*)&o0; ov.y = *(unsigned*)&o1;
    ov.z = *(unsigned*)&o2; ov.w = *(unsigned*)&o3;
    *(uint4*)(&sA[local * SROW + co]) = ov;
    __syncthreads();

    // ---- MFMA phase: wave handles col-tiles {2*wave, 2*wave+1} ----
    int rl = l16;
    int kg = sub;
    f4_t acc[2];
    acc[0] = f4_t{0.f, 0.f, 0.f, 0.f};
    acc[1] = f4_t{0.f, 0.f, 0.f, 0.f};
    const __hip_bfloat16* arow = &sA[rl * SROW + kg * 8];
#pragma unroll
    for (int ks = 0; ks < 4; ++ks) {
        bf8_t a = *(const bf8_t*)(arow + ks * 32);
#pragma unroll
        for (int t = 0; t < 2; ++t) {
            int ct = wave * 2 + t;
            bf8_t bf = *(const bf8_t*)(WT + (size_t)(ct * 16 + rl) * H + ks * 32 + kg * 8);
            acc[t] = __builtin_amdgcn_mfma_f32_16x16x32_bf16(a, bf, acc[t], 0, 0, 0);
        }
    }
    int rbase = base + kg * 4;
#pragma unroll
    for (int r = 0; r < 4; ++r) {
        int nd = rbase + r;
        if (nd < n) {
            float s = ii[nd];
#pragma unroll
            for (int t = 0; t < 2; ++t) {
                int c = (wave * 2 + t) * 16 + rl;
                float v = acc[t][r] * s + b[c];
                outp[(size_t)nd * H + c] = __float2bfloat16(fmaxf(v, 0.f));
            }
        }
    }
}

// ---------------- pooling + first head GEMV (fused), bf16 h2 input ----------------
__global__ void k_poolmlp1(const __hip_bfloat16* __restrict__ h, const int* __restrict__ gid,
                           const float* __restrict__ e1w, const float* __restrict__ e1b,
                           float* __restrict__ t1, int n) {
    __shared__ int bnd[2];
    __shared__ float row[128];
    int g = blockIdx.x, t = threadIdx.x;
    if (t == 0) {
        int lo = 0, hi = n;
        while (lo < hi) { int m = (lo + hi) >> 1; if (gid[m] < g) lo = m + 1; else hi = m; }
        bnd[0] = lo;
        int lo2 = lo, hi2 = n;
        while (lo2 < hi2) { int m = (lo2 + hi2) >> 1; if (gid[m] < g + 1) lo2 = m + 1; else hi2 = m; }
        bnd[1] = lo2;
    }
    __syncthreads();
    int beg = bnd[0], end = bnd[1];
    float s = 0.f;
    for (int i = beg; i < end; ++i) s += __bfloat162float(h[(size_t)i * H + t]);
    row[t] = s / fmaxf((float)(end - beg), 1.f);
    __syncthreads();
    float acc = e1b[t];
    for (int k = 0; k < H; ++k) acc += row[k] * e1w[k * H + t];
    t1[g * H + t] = acc;
}

// ---------------- BN stats / head ----------------
__global__ void k_bnstat(const float* __restrict__ x, float* __restrict__ stats, int G) {
    int c = blockIdx.x;
    float s = 0.f, s2 = 0.f;
    for (int g = threadIdx.x; g < G; g += blockDim.x) {
        float v = x[g * H + c];
        s += v; s2 += v * v;
    }
    __shared__ float rs[256], rs2[256];
    rs[threadIdx.x] = s; rs2[threadIdx.x] = s2;
    __syncthreads();
    for (int off = 128; off > 0; off >>= 1) {
        if (threadIdx.x < off) { rs[threadIdx.x] += rs[threadIdx.x + off]; rs2[threadIdx.x] += rs2[threadIdx.x + off]; }
        __syncthreads();
    }
    if (threadIdx.x == 0) {
        float mu = rs[0] / G;
        stats[c] = mu;
        stats[H + c] = rs2[0] / G - mu * mu;
    }
}

__global__ void k_mlp2bn(const float* __restrict__ t1, const float* __restrict__ stats,
                         const float* __restrict__ gam, const float* __restrict__ bet,
                         const float* __restrict__ W, const float* __restrict__ bias,
                         float* __restrict__ t2) {
    __shared__ float x[128];
    int g = blockIdx.x, t = threadIdx.x;
    float v = t1[g * H + t];
    v = (v - stats[t]) * rsqrtf(stats[H + t] + BN_EPS) * gam[t] + bet[t];
    x[t] = (v >= 0.f) ? v : 0.05f * v;
    __syncthreads();
    float acc = bias[t];
    for (int k = 0; k < H; ++k) acc += x[k] * W[k * H + t];
    t2[g * H + t] = acc;
}

__global__ void k_head(const float* __restrict__ t2, const float* __restrict__ stats,
                       const float* __restrict__ gam, const float* __restrict__ bet,
                       const float* __restrict__ e3w, const float* __restrict__ e3b,
                       const float* __restrict__ e4w, const float* __restrict__ e4b,
                       const float* __restrict__ e5w, const float* __restrict__ e5b,
                       float* __restrict__ out) {
    __shared__ float x[128], h3[64], h4[32];
    int g = blockIdx.x, t = threadIdx.x;
    float v = t2[g * H + t];
    v = (v - stats[t]) * rsqrtf(stats[H + t] + BN_EPS) * gam[t] + bet[t];
    x[t] = (v >= 0.f) ? v : 0.05f * v;
    __syncthreads();
    if (t < 64) {
        float a = e3b[t];
        for (int k = 0; k < 128; ++k) a += x[k] * e3w[k * 64 + t];
        h3[t] = (a >= 0.f) ? a : 0.1f * a;
    }
    __syncthreads();
    if (t < 32) {
        float a = e4b[t];
        for (int k = 0; k < 64; ++k) a += h3[k] * e4w[k * 32 + t];
        h4[t] = (a >= 0.f) ? a : 0.1f * a;
    }
    __syncthreads();
    if (t == 0) {
        float y0 = e5b[0], y1 = e5b[1];
        for (int k = 0; k < 32; ++k) {
            y0 += h4[k] * e5w[2 * k];
            y1 += h4[k] * e5w[2 * k + 1];
        }
        float m = fmaxf(y0, y1);
        float l = m + logf(expf(y0 - m) + expf(y1 - m));
        out[2 * g] = y0 - l;
        out[2 * g + 1] = y1 - l;
    }
}

extern "C" void kernel_launch(void* const* d_in, const int* in_sizes, int n_in,
                              void* d_out, int out_size, void* d_ws, size_t ws_size,
                              hipStream_t stream) {
    const int*   node_feat = (const int*)d_in[0];
    const int*   edge_src  = (const int*)d_in[1];
    const int*   edge_dst  = (const int*)d_in[2];
    const int*   graph_ids = (const int*)d_in[3];
    const float* emb  = (const float*)d_in[4];
    const float* W1   = (const float*)d_in[5];
    const float* b1   = (const float*)d_in[6];
    const float* W2   = (const float*)d_in[7];
    const float* b2   = (const float*)d_in[8];
    const float* e1_w = (const float*)d_in[9];
    const float* e1_b = (const float*)d_in[10];
    const float* e2_w = (const float*)d_in[11];
    const float* e2_b = (const float*)d_in[12];
    const float* e3_w = (const float*)d_in[13];
    const float* e3_b = (const float*)d_in[14];
    const float* e4_w = (const float*)d_in[15];
    const float* e4_b = (const float*)d_in[16];
    const float* e5_w = (const float*)d_in[17];
    const float* e5_b = (const float*)d_in[18];
    const float* bn0_g = (const float*)d_in[19];
    const float* bn0_b = (const float*)d_in[20];
    const float* bn1_g = (const float*)d_in[21];
    const float* bn1_b = (const float*)d_in[22];
    float* out = (float*)d_out;

    // workspace layout
    float* ws = (float*)d_ws;
    float* bufA = ws;                                                     // h2 (bf16, reuses f32 slot)
    __hip_bfloat16* h2bf = (__hip_bfloat16*)bufA;
    __hip_bfloat16* h1bf = (__hip_bfloat16*)(bufA + (size_t)N_NODES * H); // N*H bf16
    int*   cntO = (int*)(h1bf + (size_t)N_NODES * H);                     // 50000
    unsigned* wc = (unsigned*)(cntO + N_NODES);                           // N*32 u32 (6.4MB)
    float* ii   = (float*)(wc + (size_t)N_NODES * VOCAB);
    int*   cntI = (int*)(ii + N_NODES);
    int*   row_ptr = cntI + N_NODES;                                      // 50001 -> pad 50048
    int*   col  = row_ptr + 50048;                                        // 600000
    unsigned char* binbase = (unsigned char*)(col + N_EDGES);             // N*32
    unsigned char* rank8   = binbase + (size_t)N_NODES * VOCAB;           // 600000
    float* t1   = (float*)(rank8 + ((N_EDGES + 63) & ~63));
    float* t2   = t1 + N_GRAPHS * H;
    float* stats = t2 + N_GRAPHS * H;                                     // 512
    int*   bsum  = (int*)(stats + 4 * H);                                 // 256
    float* emb1  = (float*)(bsum + 256);                                  // 4096
    __hip_bfloat16* w2t = (__hip_bfloat16*)(emb1 + VOCAB * H);            // 16384 bf16

    // zero cntO + wc with our own kernel
    k_zero<<<(ZERO_N16 + 255) / 256, 256, 0, stream>>>((uint4*)cntO, ZERO_N16);

    k_count_prep<<<EB + 160, 256, 0, stream>>>(edge_src, cntO, emb, W1, emb1, W2, w2t);
    k_hist32<<<EB, 256, 0, stream>>>(edge_src, edge_dst, node_feat, cntO, wc, rank8, N_EDGES);
    k_nodebins<<<SCAN_BLOCKS, 256, 0, stream>>>(wc, cntI, binbase, bsum, N_NODES);
    k_scatterscan<<<SCAN_BLOCKS, 256, 0, stream>>>(cntI, bsum, row_ptr, ii, N_NODES, SCAN_BLOCKS);
    k_fill_h1<<<EB + H1_BLOCKS, 256, 0, stream>>>(edge_src, edge_dst, node_feat, row_ptr,
                                                  binbase, rank8, col,
                                                  wc, emb1, ii, cntO, b1, h1bf);

    // layer 2: fused gather->LDS->MFMA (16-deep register-staged gather), bf16 h2 out
    k_gather_mfma<<<(N_NODES + GM_NODES - 1) / GM_NODES, 256, 0, stream>>>(
        h1bf, row_ptr, col, w2t, ii, b2, h2bf, N_NODES);

    // pooling + head
    k_poolmlp1<<<N_GRAPHS, 128, 0, stream>>>(h2bf, graph_ids, e1_w, e1_b, t1, N_NODES);
    k_bnstat<<<H, 256, 0, stream>>>(t1, stats, N_GRAPHS);
    k_mlp2bn<<<N_GRAPHS, 128, 0, stream>>>(t1, stats, bn0_g, bn0_b, e2_w, e2_b, t2);
    k_bnstat<<<H, 256, 0, stream>>>(t2, stats + 2 * H, N_GRAPHS);
    k_head<<<N_GRAPHS, 128, 0, stream>>>(t2, stats + 2 * H, bn1_g, bn1_b,
                                         e3_w, e3_b, e4_w, e4_b, e5_w, e5_b, out);
}